// Round 1
// baseline (1698.264 us; speedup 1.0000x reference)
//
#include <hip/hip_runtime.h>
#include <cstdint>
#include <cstddef>

// ---------------------------------------------------------------------------
// HeteroGNN: 3-layer heterogeneous GraphSAGE on MI355X (fp32, round 1)
//   relations: 0 rates(user->item), 1 rated_by(item->user), 2 similar(item->item)
//   per relation: out = mean_neighbors(x_src) @ Wl + b + x_dst @ Wr
//   item output = 0.5*(rates + similar); relu after layers 0,1 only
// Strategy: build CSR once (reused across 3 layers), then per layer:
//   wave-per-node mean aggregation + tiled fp32 GEMM with fused epilogue.
// ---------------------------------------------------------------------------

static __host__ __device__ inline int cdiv_i(int a, int b) { return (a + b - 1) / b; }

// ---------------- CSR build ----------------

__global__ void count_edges_k(const int* __restrict__ dst, int E, int* __restrict__ cnt1) {
  int i = blockIdx.x * blockDim.x + threadIdx.x;
  if (i < E) atomicAdd(&cnt1[dst[i]], 1);
}

// Phase A: per-4096-chunk sums
__global__ void scan_partial_k(const int* __restrict__ c, int* __restrict__ part, int L) {
  __shared__ int wsums[4];
  int tid = threadIdx.x;
  int lane = tid & 63, wv = tid >> 6;
  int base = blockIdx.x * 4096 + tid * 16;
  int s = 0;
#pragma unroll
  for (int i = 0; i < 16; ++i) {
    int idx = base + i;
    if (idx < L) s += c[idx];
  }
#pragma unroll
  for (int off = 1; off < 64; off <<= 1) s += __shfl_xor(s, off, 64);
  if (lane == 0) wsums[wv] = s;
  __syncthreads();
  if (tid == 0) part[blockIdx.x] = wsums[0] + wsums[1] + wsums[2] + wsums[3];
}

// Phase B: exclusive scan of partials for all 3 relations (tiny)
__global__ void scan_partials3_k(int* part, int np0, int np1, int np2) {
  if (threadIdx.x != 0) return;
  int rel = blockIdx.x;
  int np = (rel == 0) ? np0 : (rel == 1) ? np1 : np2;
  int* p = part + rel * 32;
  int run = 0;
  for (int i = 0; i < np; ++i) { int v = p[i]; p[i] = run; run += v; }
}

// Phase C: in-place inclusive scan of each chunk + chunk offset
__global__ void scan_chunk_k(int* __restrict__ c, const int* __restrict__ part, int L) {
  __shared__ int wsums[4];
  int tid = threadIdx.x;
  int lane = tid & 63, wv = tid >> 6;
  int base = blockIdx.x * 4096 + tid * 16;
  int v[16];
  int run = 0;
#pragma unroll
  for (int i = 0; i < 16; ++i) {
    int idx = base + i;
    int x = (idx < L) ? c[idx] : 0;
    run += x;
    v[i] = run;  // thread-local inclusive
  }
  // wave inclusive scan of thread totals
  int x = run;
#pragma unroll
  for (int off = 1; off < 64; off <<= 1) {
    int y = __shfl_up(x, off, 64);
    if (lane >= off) x += y;
  }
  if (lane == 63) wsums[wv] = x;
  __syncthreads();
  int woff = 0;
  for (int w2 = 0; w2 < wv; ++w2) woff += wsums[w2];
  int offtot = part[blockIdx.x] + woff + (x - run);  // exclusive prefix for this thread
#pragma unroll
  for (int i = 0; i < 16; ++i) {
    int idx = base + i;
    if (idx < L) c[idx] = v[i] + offtot;
  }
}

__global__ void init_cursor_k(const int* __restrict__ rp, int* __restrict__ cur, int n) {
  int i = blockIdx.x * blockDim.x + threadIdx.x;
  if (i < n) cur[i] = rp[i];
}

__global__ void fill_csr_k(const int* __restrict__ src, const int* __restrict__ dst, int E,
                           int* __restrict__ cur, int* __restrict__ colv) {
  int i = blockIdx.x * blockDim.x + threadIdx.x;
  if (i < E) {
    int p = atomicAdd(&cur[dst[i]], 1);
    colv[p] = src[i];
  }
}

// ---------------- mean aggregation: one wave per dst node ----------------

template <int K>
__global__ __launch_bounds__(256) void agg_mean_k(const float* __restrict__ xsrc,
                                                  const int* __restrict__ rp,
                                                  const int* __restrict__ col,
                                                  float* __restrict__ meanv, int ndst) {
  int wv = blockIdx.x * 4 + (threadIdx.x >> 6);
  int lane = threadIdx.x & 63;
  if (wv >= ndst) return;
  int beg = rp[wv], end = rp[wv + 1];
  if (K == 64) {
    float acc = 0.f;
    int e = beg;
    for (; e + 1 < end; e += 2) {
      int s0 = col[e], s1 = col[e + 1];
      acc += xsrc[(size_t)s0 * 64 + lane];
      acc += xsrc[(size_t)s1 * 64 + lane];
    }
    if (e < end) acc += xsrc[(size_t)col[e] * 64 + lane];
    float inv = 1.f / (float)max(end - beg, 1);
    meanv[(size_t)wv * 64 + lane] = acc * inv;
  } else {
    float ax = 0.f, ay = 0.f;
    int e = beg;
    for (; e + 1 < end; e += 2) {
      int s0 = col[e], s1 = col[e + 1];
      const float2* p0 = (const float2*)(xsrc + (size_t)s0 * K);
      const float2* p1 = (const float2*)(xsrc + (size_t)s1 * K);
      float2 v0 = p0[lane], v1 = p1[lane];
      ax += v0.x + v1.x;
      ay += v0.y + v1.y;
    }
    if (e < end) {
      const float2* p = (const float2*)(xsrc + (size_t)col[e] * K);
      float2 v = p[lane];
      ax += v.x;
      ay += v.y;
    }
    float inv = 1.f / (float)max(end - beg, 1);
    ((float2*)(meanv + (size_t)wv * K))[lane] = make_float2(ax * inv, ay * inv);
  }
}

// ---------------- fused SAGE GEMM: out = scale*(A@Wl + X@Wr + b) [+out] [relu] ----
// tile: 64 rows x 64 cols, 256 threads, 4x4 register blocking, K chunked by 32.

__global__ __launch_bounds__(256) void gemm_sage_k(const float* __restrict__ A,
                                                   const float* __restrict__ X,
                                                   const float* __restrict__ Wl,
                                                   const float* __restrict__ Wr,
                                                   const float* __restrict__ bias,
                                                   float* __restrict__ out, int n, int K, int H,
                                                   float scale, int accum, int relu) {
  __shared__ float As[32][68];  // [k][row], pad 68 keeps 16B-aligned b128 reads
  __shared__ float Bs[32][64];  // [k][col]
  int tid = threadIdx.x;
  int row0 = blockIdx.x * 64;
  int col0 = blockIdx.y * 64;
  int trow = (tid >> 4) * 4;  // 0..60
  int tcol = (tid & 15) * 4;  // 0..60
  int lk = tid & 31, lr0 = tid >> 5;  // A-tile load coords
  int lh = tid & 63, lkk0 = tid >> 6; // B-tile load coords
  float c[4][4] = {};

  for (int phase = 0; phase < 2; ++phase) {
    const float* Ap = phase ? X : A;
    const float* Wp = phase ? Wr : Wl;
    for (int k0 = 0; k0 < K; k0 += 32) {
#pragma unroll
      for (int i = 0; i < 8; ++i) {
        int r = lr0 + i * 8;
        int gr = row0 + r;
        float v = (gr < n) ? Ap[(size_t)gr * K + k0 + lk] : 0.f;
        As[lk][r] = v;
      }
#pragma unroll
      for (int i = 0; i < 8; ++i) {
        int kk = lkk0 + i * 4;
        Bs[kk][lh] = Wp[(size_t)(k0 + kk) * H + col0 + lh];
      }
      __syncthreads();
#pragma unroll
      for (int kk = 0; kk < 32; ++kk) {
        float a[4], b[4];
#pragma unroll
        for (int i = 0; i < 4; ++i) a[i] = As[kk][trow + i];
#pragma unroll
        for (int j = 0; j < 4; ++j) b[j] = Bs[kk][tcol + j];
#pragma unroll
        for (int i = 0; i < 4; ++i)
#pragma unroll
          for (int j = 0; j < 4; ++j) c[i][j] = fmaf(a[i], b[j], c[i][j]);
      }
      __syncthreads();
    }
  }

#pragma unroll
  for (int i = 0; i < 4; ++i) {
    int gr = row0 + trow + i;
    if (gr >= n) continue;
#pragma unroll
    for (int j = 0; j < 4; ++j) {
      int h = col0 + tcol + j;
      float r = scale * (c[i][j] + bias[h]);
      size_t idx = (size_t)gr * H + h;
      if (accum) r += out[idx];
      if (relu) r = fmaxf(r, 0.f);
      out[idx] = r;
    }
  }
}

// ---------------------------------------------------------------------------

extern "C" void kernel_launch(void* const* d_in, const int* in_sizes, int n_in, void* d_out,
                              int out_size, void* d_ws, size_t ws_size, hipStream_t stream) {
  const int NU = 100000, NI = 30000;
  const int O = 64;

  const float* x_user = (const float*)d_in[0];
  const float* x_item = (const float*)d_in[1];
  const int* e_rates = (const int*)d_in[2];
  const int* e_rated = (const int*)d_in[3];
  const int* e_sim = (const int*)d_in[4];
  const int ER = in_sizes[2] / 2;
  const int ERB = in_sizes[3] / 2;
  const int ES = in_sizes[4] / 2;
  const float* Wl0 = (const float*)d_in[5];
  const float* bl0 = (const float*)d_in[6];
  const float* Wr0 = (const float*)d_in[7];
  const float* Wl1 = (const float*)d_in[8];
  const float* bl1 = (const float*)d_in[9];
  const float* Wr1 = (const float*)d_in[10];
  const float* Wl2 = (const float*)d_in[11];
  const float* bl2 = (const float*)d_in[12];
  const float* Wr2 = (const float*)d_in[13];
  float* outp = (float*)d_out;

  // ---- workspace layout ----
  char* wsc = (char*)d_ws;
  size_t off = 0;
  auto alloc = [&](size_t bytes) -> char* {
    size_t cur = (off + 255) & ~(size_t)255;
    off = cur + bytes;
    return wsc + cur;
  };
  int* rp_all = (int*)alloc((size_t)(NI + 1 + NU + 1 + NI + 1) * 4);
  int* rp_r = rp_all;
  int* rp_u = rp_r + (NI + 1);
  int* rp_s = rp_u + (NU + 1);
  int* cur_r = (int*)alloc((size_t)NI * 4);
  int* cur_u = (int*)alloc((size_t)NU * 4);
  int* cur_s = (int*)alloc((size_t)NI * 4);
  int* col_r = (int*)alloc((size_t)ER * 4);
  int* col_u = (int*)alloc((size_t)ERB * 4);
  int* col_s = (int*)alloc((size_t)ES * 4);
  int* part = (int*)alloc(3 * 32 * 4);
  float* mean_u = (float*)alloc((size_t)NU * 128 * 4);
  float* mean_i = (float*)alloc((size_t)NI * 128 * 4);
  float* hu_a = (float*)alloc((size_t)NU * 128 * 4);
  float* hu_b = (float*)alloc((size_t)NU * 128 * 4);
  float* hi_a = (float*)alloc((size_t)NI * 128 * 4);
  float* hi_b = (float*)alloc((size_t)NI * 128 * 4);
  (void)ws_size;

  // ---- CSR build (layer-invariant) ----
  hipMemsetAsync(rp_all, 0, (size_t)(NI + 1 + NU + 1 + NI + 1) * 4, stream);
  count_edges_k<<<cdiv_i(ER, 256), 256, 0, stream>>>(e_rates + ER, ER, rp_r + 1);
  count_edges_k<<<cdiv_i(ERB, 256), 256, 0, stream>>>(e_rated + ERB, ERB, rp_u + 1);
  count_edges_k<<<cdiv_i(ES, 256), 256, 0, stream>>>(e_sim + ES, ES, rp_s + 1);

  int npr = cdiv_i(NI + 1, 4096), npu = cdiv_i(NU + 1, 4096), nps = cdiv_i(NI + 1, 4096);
  scan_partial_k<<<npr, 256, 0, stream>>>(rp_r, part + 0, NI + 1);
  scan_partial_k<<<npu, 256, 0, stream>>>(rp_u, part + 32, NU + 1);
  scan_partial_k<<<nps, 256, 0, stream>>>(rp_s, part + 64, NI + 1);
  scan_partials3_k<<<3, 64, 0, stream>>>(part, npr, npu, nps);
  scan_chunk_k<<<npr, 256, 0, stream>>>(rp_r, part + 0, NI + 1);
  scan_chunk_k<<<npu, 256, 0, stream>>>(rp_u, part + 32, NU + 1);
  scan_chunk_k<<<nps, 256, 0, stream>>>(rp_s, part + 64, NI + 1);
  init_cursor_k<<<cdiv_i(NI, 256), 256, 0, stream>>>(rp_r, cur_r, NI);
  init_cursor_k<<<cdiv_i(NU, 256), 256, 0, stream>>>(rp_u, cur_u, NU);
  init_cursor_k<<<cdiv_i(NI, 256), 256, 0, stream>>>(rp_s, cur_s, NI);
  fill_csr_k<<<cdiv_i(ER, 256), 256, 0, stream>>>(e_rates, e_rates + ER, ER, cur_r, col_r);
  fill_csr_k<<<cdiv_i(ERB, 256), 256, 0, stream>>>(e_rated, e_rated + ERB, ERB, cur_u, col_u);
  fill_csr_k<<<cdiv_i(ES, 256), 256, 0, stream>>>(e_sim, e_sim + ES, ES, cur_s, col_s);

  // ---- one hetero layer ----
  auto run_layer = [&](const float* xu, const float* xi, int Kd, int Ho, const float* Wl,
                       const float* bl, const float* Wr, float* ou, float* oi, int relu) {
    size_t WS = (size_t)Kd * Ho;  // per-relation weight stride
    // items, relation 0 (rates: user -> item)
    if (Kd == 64)
      agg_mean_k<64><<<cdiv_i(NI, 4), 256, 0, stream>>>(xu, rp_r, col_r, mean_i, NI);
    else
      agg_mean_k<128><<<cdiv_i(NI, 4), 256, 0, stream>>>(xu, rp_r, col_r, mean_i, NI);
    gemm_sage_k<<<dim3(cdiv_i(NI, 64), Ho / 64), 256, 0, stream>>>(
        mean_i, xi, Wl + 0 * WS, Wr + 0 * WS, bl + 0 * Ho, oi, NI, Kd, Ho, 0.5f, 0, 0);
    // items, relation 2 (similar: item -> item), accumulate + optional relu
    if (Kd == 64)
      agg_mean_k<64><<<cdiv_i(NI, 4), 256, 0, stream>>>(xi, rp_s, col_s, mean_i, NI);
    else
      agg_mean_k<128><<<cdiv_i(NI, 4), 256, 0, stream>>>(xi, rp_s, col_s, mean_i, NI);
    gemm_sage_k<<<dim3(cdiv_i(NI, 64), Ho / 64), 256, 0, stream>>>(
        mean_i, xi, Wl + 2 * WS, Wr + 2 * WS, bl + 2 * Ho, oi, NI, Kd, Ho, 0.5f, 1, relu);
    // users, relation 1 (rated_by: item -> user)
    if (Kd == 64)
      agg_mean_k<64><<<cdiv_i(NU, 4), 256, 0, stream>>>(xi, rp_u, col_u, mean_u, NU);
    else
      agg_mean_k<128><<<cdiv_i(NU, 4), 256, 0, stream>>>(xi, rp_u, col_u, mean_u, NU);
    gemm_sage_k<<<dim3(cdiv_i(NU, 64), Ho / 64), 256, 0, stream>>>(
        mean_u, xu, Wl + 1 * WS, Wr + 1 * WS, bl + 1 * Ho, ou, NU, Kd, Ho, 1.0f, 0, relu);
  };

  run_layer(x_user, x_item, 64, 128, Wl0, bl0, Wr0, hu_a, hi_a, 1);
  run_layer(hu_a, hi_a, 128, 128, Wl1, bl1, Wr1, hu_b, hi_b, 1);
  run_layer(hu_b, hi_b, 128, 64, Wl2, bl2, Wr2, outp, outp + (size_t)NU * O, 0);
}

// Round 2
// 1326.272 us; speedup vs baseline: 1.2805x; 1.2805x over previous
//
#include <hip/hip_runtime.h>
#include <cstdint>
#include <cstddef>

// ---------------------------------------------------------------------------
// HeteroGNN round 2: bf16 activations + MFMA GEMM, fp32 accumulation.
//   CSR built once; per layer: bf16 mean-aggregation (wave/node) +
//   fused MFMA GEMM out = scale*(mean@Wl + b + x@Wr) [+accum] [relu],
//   weights pre-transposed to bf16 [H][K] so B-fragments are ds_read_b128.
// MFMA 16x16x32_bf16 layouts (HW-verified, learn_hip m89/m120):
//   A/B frag: elem[m|n = lane&15][k = (lane>>4)*8 + j]
//   C/D:      col = lane&15, row = (lane>>4)*4 + reg
// ---------------------------------------------------------------------------

static __host__ __device__ inline int cdiv_i(int a, int b) { return (a + b - 1) / b; }

typedef __attribute__((ext_vector_type(8))) short bf16x8;
typedef __attribute__((ext_vector_type(4))) float f32x4;

__device__ inline float bf_lo(unsigned u) { return __uint_as_float(u << 16); }
__device__ inline float bf_hi(unsigned u) { return __uint_as_float(u & 0xffff0000u); }
__device__ inline unsigned short f2bf(float f) {
  unsigned u = __float_as_uint(f);
  return (unsigned short)((u + 0x7fffu + ((u >> 16) & 1u)) >> 16);  // RNE
}

// ---------------- CSR build (unchanged from round 1) ----------------

__global__ void count_edges_k(const int* __restrict__ dst, int E, int* __restrict__ cnt1) {
  int i = blockIdx.x * blockDim.x + threadIdx.x;
  if (i < E) atomicAdd(&cnt1[dst[i]], 1);
}

__global__ void scan_partial_k(const int* __restrict__ c, int* __restrict__ part, int L) {
  __shared__ int wsums[4];
  int tid = threadIdx.x;
  int lane = tid & 63, wv = tid >> 6;
  int base = blockIdx.x * 4096 + tid * 16;
  int s = 0;
#pragma unroll
  for (int i = 0; i < 16; ++i) {
    int idx = base + i;
    if (idx < L) s += c[idx];
  }
#pragma unroll
  for (int off = 1; off < 64; off <<= 1) s += __shfl_xor(s, off, 64);
  if (lane == 0) wsums[wv] = s;
  __syncthreads();
  if (tid == 0) part[blockIdx.x] = wsums[0] + wsums[1] + wsums[2] + wsums[3];
}

__global__ void scan_partials3_k(int* part, int np0, int np1, int np2) {
  if (threadIdx.x != 0) return;
  int rel = blockIdx.x;
  int np = (rel == 0) ? np0 : (rel == 1) ? np1 : np2;
  int* p = part + rel * 32;
  int run = 0;
  for (int i = 0; i < np; ++i) { int v = p[i]; p[i] = run; run += v; }
}

__global__ void scan_chunk_k(int* __restrict__ c, const int* __restrict__ part, int L) {
  __shared__ int wsums[4];
  int tid = threadIdx.x;
  int lane = tid & 63, wv = tid >> 6;
  int base = blockIdx.x * 4096 + tid * 16;
  int v[16];
  int run = 0;
#pragma unroll
  for (int i = 0; i < 16; ++i) {
    int idx = base + i;
    int x = (idx < L) ? c[idx] : 0;
    run += x;
    v[i] = run;
  }
  int x = run;
#pragma unroll
  for (int off = 1; off < 64; off <<= 1) {
    int y = __shfl_up(x, off, 64);
    if (lane >= off) x += y;
  }
  if (lane == 63) wsums[wv] = x;
  __syncthreads();
  int woff = 0;
  for (int w2 = 0; w2 < wv; ++w2) woff += wsums[w2];
  int offtot = part[blockIdx.x] + woff + (x - run);
#pragma unroll
  for (int i = 0; i < 16; ++i) {
    int idx = base + i;
    if (idx < L) c[idx] = v[i] + offtot;
  }
}

__global__ void init_cursor_k(const int* __restrict__ rp, int* __restrict__ cur, int n) {
  int i = blockIdx.x * blockDim.x + threadIdx.x;
  if (i < n) cur[i] = rp[i];
}

__global__ void fill_csr_k(const int* __restrict__ src, const int* __restrict__ dst, int E,
                           int* __restrict__ cur, int* __restrict__ colv) {
  int i = blockIdx.x * blockDim.x + threadIdx.x;
  if (i < E) {
    int p = atomicAdd(&cur[dst[i]], 1);
    colv[p] = src[i];
  }
}

// ---------------- dtype conversion ----------------

// fp32 -> bf16, 4 elems/thread
__global__ void cvt_f32_bf16_k(const float* __restrict__ in, unsigned short* __restrict__ out,
                               int n4) {
  int i = blockIdx.x * blockDim.x + threadIdx.x;
  if (i >= n4) return;
  float4 v = ((const float4*)in)[i];
  uint2 u;
  u.x = (unsigned)f2bf(v.x) | ((unsigned)f2bf(v.y) << 16);
  u.y = (unsigned)f2bf(v.z) | ((unsigned)f2bf(v.w) << 16);
  ((uint2*)out)[i] = u;
}

// fp32 [3][K][H] -> bf16 [3][H][K] (transpose per relation)
__global__ void cvt_w_k(const float* __restrict__ W, unsigned short* __restrict__ Wt, int K,
                        int H, int total) {
  int idx = blockIdx.x * blockDim.x + threadIdx.x;
  if (idx >= total) return;
  int kh = K * H;
  int rel = idx / kh;
  int r2 = idx - rel * kh;
  int k = r2 / H;
  int h = r2 - k * H;
  Wt[rel * kh + h * K + k] = f2bf(W[idx]);
}

// ---------------- mean aggregation (bf16 in, bf16 out, fp32 acc) ----------

// K=128: one wave per dst node; lane loads uint (2 bf16) -> 256 B/row coalesced
__global__ __launch_bounds__(256) void agg_mean_bf128_k(const unsigned short* __restrict__ xsrc,
                                                        const int* __restrict__ rp,
                                                        const int* __restrict__ col,
                                                        unsigned short* __restrict__ meanv,
                                                        int ndst) {
  int wv = blockIdx.x * 4 + (threadIdx.x >> 6);
  int lane = threadIdx.x & 63;
  if (wv >= ndst) return;
  int beg = rp[wv], end = rp[wv + 1];
  float ax = 0.f, ay = 0.f;
  int e = beg;
  for (; e + 1 < end; e += 2) {
    int s0 = col[e], s1 = col[e + 1];
    unsigned u0 = ((const unsigned*)(xsrc + (size_t)s0 * 128))[lane];
    unsigned u1 = ((const unsigned*)(xsrc + (size_t)s1 * 128))[lane];
    ax += bf_lo(u0) + bf_lo(u1);
    ay += bf_hi(u0) + bf_hi(u1);
  }
  if (e < end) {
    unsigned u = ((const unsigned*)(xsrc + (size_t)col[e] * 128))[lane];
    ax += bf_lo(u);
    ay += bf_hi(u);
  }
  float inv = 1.f / (float)max(end - beg, 1);
  unsigned o = (unsigned)f2bf(ax * inv) | ((unsigned)f2bf(ay * inv) << 16);
  ((unsigned*)(meanv + (size_t)wv * 128))[lane] = o;
}

// K=64: one wave per dst node, two edges per iteration (half-wave each)
__global__ __launch_bounds__(256) void agg_mean_bf64_k(const unsigned short* __restrict__ xsrc,
                                                       const int* __restrict__ rp,
                                                       const int* __restrict__ col,
                                                       unsigned short* __restrict__ meanv,
                                                       int ndst) {
  int wv = blockIdx.x * 4 + (threadIdx.x >> 6);
  int lane = threadIdx.x & 63;
  int h = lane >> 5, j = lane & 31;
  if (wv >= ndst) return;
  int beg = rp[wv], end = rp[wv + 1];
  float ax = 0.f, ay = 0.f;
  for (int e = beg; e < end; e += 2) {
    int idx = e + h;
    if (idx < end) {
      int s = col[idx];
      unsigned u = ((const unsigned*)(xsrc + (size_t)s * 64))[j];
      ax += bf_lo(u);
      ay += bf_hi(u);
    }
  }
  ax += __shfl_xor(ax, 32, 64);
  ay += __shfl_xor(ay, 32, 64);
  if (h == 0) {
    float inv = 1.f / (float)max(end - beg, 1);
    unsigned o = (unsigned)f2bf(ax * inv) | ((unsigned)f2bf(ay * inv) << 16);
    ((unsigned*)(meanv + (size_t)wv * 64))[j] = o;
  }
}

// ---------------- MFMA GEMM: out = scale*(A@Wl + b) + scale*(X@Wr) ----------
// A,X: bf16 row-major [n][K]; Wl,Wr: bf16 TRANSPOSED [H][K]; acc fp32.
// BM=128, BN=64, 256 threads = 4 waves, wave computes 32x64 via 2x4 16x16 tiles.

__global__ __launch_bounds__(256) void gemm_mfma_k(
    const unsigned short* __restrict__ A, const unsigned short* __restrict__ X,
    const unsigned short* __restrict__ Wl, const unsigned short* __restrict__ Wr,
    const float* __restrict__ bias, const float* __restrict__ accum_in,
    float* __restrict__ out_f32, unsigned short* __restrict__ out_bf16, int n, int K, int H,
    float scale, int relu) {
  __shared__ alignas(16) unsigned short As[128 * 32];  // [row][k] row-major
  __shared__ alignas(16) unsigned short Bs[64 * 32];   // [col][k] (weights pre-transposed)
  int tid = threadIdx.x;
  int row0 = blockIdx.x * 128;
  int col0 = blockIdx.y * 64;
  int w = tid >> 6, l = tid & 63;
  int lr = l & 15, lq = l >> 4;

  f32x4 acc[2][4] = {};

  for (int phase = 0; phase < 2; ++phase) {
    const unsigned short* Ap = phase ? X : A;
    const unsigned short* Wp = phase ? Wr : Wl;
    for (int k0 = 0; k0 < K; k0 += 32) {
      // stage A: 128 rows x 32 k (64 B/row) -> 512 x 16 B chunks, 2 per thread
      {
        int r = tid >> 2, c = tid & 3;
#pragma unroll
        for (int i = 0; i < 2; ++i) {
          int rr = r + i * 64;
          int gr = row0 + rr;
          uint4 v = make_uint4(0, 0, 0, 0);
          if (gr < n) v = *(const uint4*)(Ap + (size_t)gr * K + k0 + c * 8);
          *(uint4*)(As + rr * 32 + c * 8) = v;
        }
        // stage B: 64 cols x 32 k, 1 chunk per thread
        int nn = tid >> 2;
        *(uint4*)(Bs + nn * 32 + c * 8) =
            *(const uint4*)(Wp + (size_t)(col0 + nn) * K + k0 + c * 8);
      }
      __syncthreads();
      bf16x8 af[2], bfr[4];
#pragma unroll
      for (int t = 0; t < 2; ++t)
        af[t] = *(const bf16x8*)(As + (w * 32 + t * 16 + lr) * 32 + lq * 8);
#pragma unroll
      for (int c = 0; c < 4; ++c)
        bfr[c] = *(const bf16x8*)(Bs + (c * 16 + lr) * 32 + lq * 8);
#pragma unroll
      for (int t = 0; t < 2; ++t)
#pragma unroll
        for (int c = 0; c < 4; ++c)
          acc[t][c] = __builtin_amdgcn_mfma_f32_16x16x32_bf16(af[t], bfr[c], acc[t][c], 0, 0, 0);
      __syncthreads();
    }
  }

  // epilogue: C/D layout col=lane&15, row=lq*4+reg
#pragma unroll
  for (int t = 0; t < 2; ++t) {
#pragma unroll
    for (int c = 0; c < 4; ++c) {
      int gc = col0 + c * 16 + lr;
      float b = bias[gc];
#pragma unroll
      for (int r = 0; r < 4; ++r) {
        int gr = row0 + w * 32 + t * 16 + lq * 4 + r;
        if (gr >= n) continue;
        float val = scale * (acc[t][c][r] + b);
        size_t idx = (size_t)gr * H + gc;
        if (accum_in) val += accum_in[idx];
        if (relu) val = fmaxf(val, 0.f);
        if (out_f32) out_f32[idx] = val;
        if (out_bf16) out_bf16[idx] = f2bf(val);
      }
    }
  }
}

// ---------------------------------------------------------------------------

extern "C" void kernel_launch(void* const* d_in, const int* in_sizes, int n_in, void* d_out,
                              int out_size, void* d_ws, size_t ws_size, hipStream_t stream) {
  const int NU = 100000, NI = 30000;
  const int O = 64;

  const float* x_user = (const float*)d_in[0];
  const float* x_item = (const float*)d_in[1];
  const int* e_rates = (const int*)d_in[2];
  const int* e_rated = (const int*)d_in[3];
  const int* e_sim = (const int*)d_in[4];
  const int ER = in_sizes[2] / 2;
  const int ERB = in_sizes[3] / 2;
  const int ES = in_sizes[4] / 2;
  const float* Wl0 = (const float*)d_in[5];
  const float* bl0 = (const float*)d_in[6];
  const float* Wr0 = (const float*)d_in[7];
  const float* Wl1 = (const float*)d_in[8];
  const float* bl1 = (const float*)d_in[9];
  const float* Wr1 = (const float*)d_in[10];
  const float* Wl2 = (const float*)d_in[11];
  const float* bl2 = (const float*)d_in[12];
  const float* Wr2 = (const float*)d_in[13];
  float* outp = (float*)d_out;

  // ---- workspace layout ----
  char* wsc = (char*)d_ws;
  size_t off = 0;
  auto alloc = [&](size_t bytes) -> char* {
    size_t cur = (off + 255) & ~(size_t)255;
    off = cur + bytes;
    return wsc + cur;
  };
  int* rp_all = (int*)alloc((size_t)(NI + 1 + NU + 1 + NI + 1) * 4);
  int* rp_r = rp_all;
  int* rp_u = rp_r + (NI + 1);
  int* rp_s = rp_u + (NU + 1);
  int* cur_r = (int*)alloc((size_t)NI * 4);
  int* cur_u = (int*)alloc((size_t)NU * 4);
  int* cur_s = (int*)alloc((size_t)NI * 4);
  int* col_r = (int*)alloc((size_t)ER * 4);
  int* col_u = (int*)alloc((size_t)ERB * 4);
  int* col_s = (int*)alloc((size_t)ES * 4);
  int* part = (int*)alloc(3 * 32 * 4);
  typedef unsigned short u16;
  u16* xu_bf = (u16*)alloc((size_t)NU * 64 * 2);
  u16* xi_bf = (u16*)alloc((size_t)NI * 64 * 2);
  u16* mean_u = (u16*)alloc((size_t)NU * 128 * 2);
  u16* mean_i = (u16*)alloc((size_t)NI * 128 * 2);
  u16* hu_a = (u16*)alloc((size_t)NU * 128 * 2);
  u16* hu_b = (u16*)alloc((size_t)NU * 128 * 2);
  u16* hi_a = (u16*)alloc((size_t)NI * 128 * 2);
  u16* hi_b = (u16*)alloc((size_t)NI * 128 * 2);
  float* tmp_i = (float*)alloc((size_t)NI * 128 * 4);
  u16* wl0t = (u16*)alloc((size_t)3 * 64 * 128 * 2);
  u16* wr0t = (u16*)alloc((size_t)3 * 64 * 128 * 2);
  u16* wl1t = (u16*)alloc((size_t)3 * 128 * 128 * 2);
  u16* wr1t = (u16*)alloc((size_t)3 * 128 * 128 * 2);
  u16* wl2t = (u16*)alloc((size_t)3 * 128 * 64 * 2);
  u16* wr2t = (u16*)alloc((size_t)3 * 128 * 64 * 2);
  (void)ws_size;

  // ---- CSR build (layer-invariant) ----
  hipMemsetAsync(rp_all, 0, (size_t)(NI + 1 + NU + 1 + NI + 1) * 4, stream);
  count_edges_k<<<cdiv_i(ER, 256), 256, 0, stream>>>(e_rates + ER, ER, rp_r + 1);
  count_edges_k<<<cdiv_i(ERB, 256), 256, 0, stream>>>(e_rated + ERB, ERB, rp_u + 1);
  count_edges_k<<<cdiv_i(ES, 256), 256, 0, stream>>>(e_sim + ES, ES, rp_s + 1);

  int npr = cdiv_i(NI + 1, 4096), npu = cdiv_i(NU + 1, 4096), nps = cdiv_i(NI + 1, 4096);
  scan_partial_k<<<npr, 256, 0, stream>>>(rp_r, part + 0, NI + 1);
  scan_partial_k<<<npu, 256, 0, stream>>>(rp_u, part + 32, NU + 1);
  scan_partial_k<<<nps, 256, 0, stream>>>(rp_s, part + 64, NI + 1);
  scan_partials3_k<<<3, 64, 0, stream>>>(part, npr, npu, nps);
  scan_chunk_k<<<npr, 256, 0, stream>>>(rp_r, part + 0, NI + 1);
  scan_chunk_k<<<npu, 256, 0, stream>>>(rp_u, part + 32, NU + 1);
  scan_chunk_k<<<nps, 256, 0, stream>>>(rp_s, part + 64, NI + 1);
  init_cursor_k<<<cdiv_i(NI, 256), 256, 0, stream>>>(rp_r, cur_r, NI);
  init_cursor_k<<<cdiv_i(NU, 256), 256, 0, stream>>>(rp_u, cur_u, NU);
  init_cursor_k<<<cdiv_i(NI, 256), 256, 0, stream>>>(rp_s, cur_s, NI);
  fill_csr_k<<<cdiv_i(ER, 256), 256, 0, stream>>>(e_rates, e_rates + ER, ER, cur_r, col_r);
  fill_csr_k<<<cdiv_i(ERB, 256), 256, 0, stream>>>(e_rated, e_rated + ERB, ERB, cur_u, col_u);
  fill_csr_k<<<cdiv_i(ES, 256), 256, 0, stream>>>(e_sim, e_sim + ES, ES, cur_s, col_s);

  // ---- dtype conversions ----
  cvt_f32_bf16_k<<<cdiv_i(NU * 64 / 4, 256), 256, 0, stream>>>(x_user, xu_bf, NU * 64 / 4);
  cvt_f32_bf16_k<<<cdiv_i(NI * 64 / 4, 256), 256, 0, stream>>>(x_item, xi_bf, NI * 64 / 4);
  cvt_w_k<<<cdiv_i(3 * 64 * 128, 256), 256, 0, stream>>>(Wl0, wl0t, 64, 128, 3 * 64 * 128);
  cvt_w_k<<<cdiv_i(3 * 64 * 128, 256), 256, 0, stream>>>(Wr0, wr0t, 64, 128, 3 * 64 * 128);
  cvt_w_k<<<cdiv_i(3 * 128 * 128, 256), 256, 0, stream>>>(Wl1, wl1t, 128, 128, 3 * 128 * 128);
  cvt_w_k<<<cdiv_i(3 * 128 * 128, 256), 256, 0, stream>>>(Wr1, wr1t, 128, 128, 3 * 128 * 128);
  cvt_w_k<<<cdiv_i(3 * 128 * 64, 256), 256, 0, stream>>>(Wl2, wl2t, 128, 64, 3 * 128 * 64);
  cvt_w_k<<<cdiv_i(3 * 128 * 64, 256), 256, 0, stream>>>(Wr2, wr2t, 128, 64, 3 * 128 * 64);

  // ---- one hetero layer (bf16 activations in; bf16 or fp32 out) ----
  auto agg = [&](const u16* xs, const int* rp, const int* col, u16* mv, int nd, int Kd) {
    if (Kd == 64)
      agg_mean_bf64_k<<<cdiv_i(nd, 4), 256, 0, stream>>>(xs, rp, col, mv, nd);
    else
      agg_mean_bf128_k<<<cdiv_i(nd, 4), 256, 0, stream>>>(xs, rp, col, mv, nd);
  };

  auto run_layer = [&](const u16* xu, const u16* xi, int Kd, int Ho, const u16* Wlt,
                       const float* bl, const u16* Wrt, u16* ou_bf, u16* oi_bf, float* ou_f,
                       float* oi_f, int relu) {
    size_t WS = (size_t)Kd * Ho;
    dim3 gi(cdiv_i(NI, 128), Ho / 64), gu(cdiv_i(NU, 128), Ho / 64);
    // items pass 1: relation 0 (rates: user -> item), fp32 partial
    agg(xu, rp_r, col_r, mean_i, NI, Kd);
    gemm_mfma_k<<<gi, 256, 0, stream>>>(mean_i, xi, Wlt + 0 * WS, Wrt + 0 * WS, bl + 0 * Ho,
                                        nullptr, tmp_i, nullptr, NI, Kd, Ho, 0.5f, 0);
    // items pass 2: relation 2 (similar: item -> item), accumulate + relu
    agg(xi, rp_s, col_s, mean_i, NI, Kd);
    gemm_mfma_k<<<gi, 256, 0, stream>>>(mean_i, xi, Wlt + 2 * WS, Wrt + 2 * WS, bl + 2 * Ho,
                                        tmp_i, oi_f, oi_bf, NI, Kd, Ho, 0.5f, relu);
    // users: relation 1 (rated_by: item -> user)
    agg(xi, rp_u, col_u, mean_u, NU, Kd);
    gemm_mfma_k<<<gu, 256, 0, stream>>>(mean_u, xu, Wlt + 1 * WS, Wrt + 1 * WS, bl + 1 * Ho,
                                        nullptr, ou_f, ou_bf, NU, Kd, Ho, 1.0f, relu);
  };

  run_layer(xu_bf, xi_bf, 64, 128, wl0t, bl0, wr0t, hu_a, hi_a, nullptr, nullptr, 1);
  run_layer(hu_a, hi_a, 128, 128, wl1t, bl1, wr1t, hu_b, hi_b, nullptr, nullptr, 1);
  run_layer(hu_b, hi_b, 128, 64, wl2t, bl2, wr2t, nullptr, nullptr, outp, outp + (size_t)NU * O,
            0);
}